// Round 7
// baseline (219.173 us; speedup 1.0000x reference)
//
#include <hip/hip_runtime.h>

constexpr int Lc = 16;
constexpr int Cc = 16;
constexpr int Hc = 128;
constexpr int Wc = 256;
constexpr float DECAYc = 0.1f;
constexpr int HWc = Hc * Wc;
constexpr int NBLK = 512;            // full grid; 2 blocks/CU, >=3x residency margin

// ---------------------------------------------------------------------------
// Fused single-dispatch kernel with software grid barrier.
// Phase A: each block transposes 1024 px of frame (b>>5) from (L,C,H,W) to
//          channels-last imgT (L,H,W,C). Release-signal `done`, acquire-spin
//          until all 512 blocks signaled (once per kernel; guard-bounded).
// Phase B: R4 t-merge structure — block owns 64 px for ALL 16 t's, k outer
//          0..14 (wave-uniform), t inner unrolled, branch-free t>k body.
//          Band-swizzle (b&7) for per-XCD L2 locality; strict k-lockstep.
//          Lane = 4*wq+q: 4 lanes cover one pixel's 64B channels-last line ->
//          every gather instr = 16 full-line requests (minimum).
//          k==t identity samples (weight 1, exact coords) added in epilogue.
// ---------------------------------------------------------------------------
__global__ __launch_bounds__(256) void gridsample_fused_sw(
    const float* __restrict__ img,       // (L, C, H, W)
    const float* __restrict__ cum_flow,  // (L, 2, H, W)
    const float* __restrict__ mask,      // (L, L)
    const float* __restrict__ decay,     // (L, L)
    float* __restrict__ imgT,            // ws: (L, H, W, C)
    unsigned int* __restrict__ done,     // ws: barrier counter (memset 0)
    float* __restrict__ out)             // (L, C, H, W)
{
    const int tid = threadIdx.x;
    const int q  = tid & 3;              // channel quarter
    const int wq = tid >> 2;             // pixel-in-group 0..63
    const int b = blockIdx.x;            // 0..511

    // ---- Phase A: transpose 1024 px of frame kf ----
    {
        const int kf  = b >> 5;          // 0..15 (32 blocks per frame)
        const int px0 = (b & 31) * 1024;
        const float* __restrict__ srcb = img + (size_t)kf * Cc * HWc;
#pragma unroll
        for (int rr = 0; rr < 16; ++rr) {
            const int px = px0 + rr * 64 + wq;
            float4 v;
            v.x = srcb[(4 * q + 0) * HWc + px];
            v.y = srcb[(4 * q + 1) * HWc + px];
            v.z = srcb[(4 * q + 2) * HWc + px];
            v.w = srcb[(4 * q + 3) * HWc + px];
            ((float4*)(imgT + ((size_t)kf * HWc + px) * Cc))[q] = v;
        }
    }
    __syncthreads();
    if (tid == 0)
        __hip_atomic_fetch_add(done, 1u, __ATOMIC_RELEASE, __HIP_MEMORY_SCOPE_AGENT);

    // Weight table while other blocks finish.
    __shared__ float wtab[Lc * Lc];
    if (tid < Lc * Lc)
        wtab[tid] = mask[tid] * __expf(-DECAYc * decay[tid]);

    // ---- software grid barrier (once; guard-bounded hang protection) ----
    if (tid == 0) {
        int guard = 0;
        while (__hip_atomic_load(done, __ATOMIC_ACQUIRE, __HIP_MEMORY_SCOPE_AGENT)
               < (unsigned)NBLK) {
            __builtin_amdgcn_s_sleep(8);
            if (++guard > (1 << 22)) break;   // ~0.5s: fail visibly, don't hang
        }
    }
    __syncthreads();

    // ---- Phase B: t-merged warp-accumulate ----
    const int band = b & 7;              // 16-row band (XCD heuristic)
    const int sub  = b >> 3;             // 0..63
    const int h = band * 16 + (sub >> 2);
    const int w = (sub & 3) * 64 + wq;
    const int pix = h * Wc + w;

    const float base_x = w * (2.0f / Wc) - 1.0f + 1.0f / Wc;
    const float base_y = h * (2.0f / Hc) - 1.0f + 1.0f / Hc;

    // Pre-added per-t terms: mod-arg = sx1[t] - fxk ; gy+1 = sy1[t] - fyk
    float sx1[Lc], sy1[Lc];
#pragma unroll
    for (int t = 0; t < Lc; ++t) {
        sx1[t] = base_x + cum_flow[(t * 2 + 0) * HWc + pix] + 1.0f;
        sy1[t] = base_y + cum_flow[(t * 2 + 1) * HWc + pix] + 1.0f;
    }

    float4 acc[Lc];
#pragma unroll
    for (int t = 0; t < Lc; ++t) acc[t] = make_float4(0.f, 0.f, 0.f, 0.f);

    for (int k = 0; k < Lc - 1; ++k) {   // k==15 contributes only identity
        const float fxk = cum_flow[(k * 2 + 0) * HWc + pix];
        const float fyk = cum_flow[(k * 2 + 1) * HWc + pix];
        const float* __restrict__ bk = imgT + (size_t)k * HWc * Cc;

#pragma unroll
        for (int t = 0; t < Lc; ++t) {
            if (t <= k) continue;        // wave-uniform (k in SGPR)
            const float wkt = wtab[t * Lc + k];

            // m = mod(gx+1, 2);  ix = m*W/2 - 0.5
            float m = sx1[t] - fxk;
            m -= 2.0f * floorf(m * 0.5f);
            const float ix = m * (Wc * 0.5f) - 0.5f;
            const float iy = (sy1[t] - fyk) * (Hc * 0.5f) - 0.5f;

            const float x0f = floorf(ix);
            const float y0f = floorf(iy);
            const float wx = ix - x0f;
            const float wy = iy - y0f;

            const int x0 = (int)x0f;
            const int y0 = (int)y0f;
            const int x0r = x0 & (Wc - 1);
            const int x1r = (x0 + 1) & (Wc - 1);
            const int y0c = min(max(y0, 0), Hc - 1);
            const int y1c = min(max(y0 + 1, 0), Hc - 1);

            const float wb = wkt * wy;
            const float wa = wkt - wb;
            const float omx = 1.0f - wx;
            const float a00 = wa * omx;
            const float a10 = wa * wx;
            const float a01 = wb * omx;
            const float a11 = wb * wx;

            const float4 v00 = ((const float4*)(bk + (y0c * Wc + x0r) * Cc))[q];
            const float4 v10 = ((const float4*)(bk + (y0c * Wc + x1r) * Cc))[q];
            const float4 v01 = ((const float4*)(bk + (y1c * Wc + x0r) * Cc))[q];
            const float4 v11 = ((const float4*)(bk + (y1c * Wc + x1r) * Cc))[q];

            acc[t].x += a00 * v00.x + a10 * v10.x + a01 * v01.x + a11 * v11.x;
            acc[t].y += a00 * v00.y + a10 * v10.y + a01 * v01.y + a11 * v11.y;
            acc[t].z += a00 * v00.z + a10 * v10.z + a01 * v01.z + a11 * v11.z;
            acc[t].w += a00 * v00.w + a10 * v10.w + a01 * v01.w + a11 * v11.w;
        }
    }

    // Epilogue: add identity sample (t==k term) and store.
#pragma unroll
    for (int t = 0; t < Lc; ++t) {
        const float4 idv =
            ((const float4*)(imgT + ((size_t)t * HWc + pix) * Cc))[q];
        float* __restrict__ op = out + ((size_t)t * Cc + 4 * q) * HWc + pix;
        op[0 * HWc] = acc[t].x + idv.x;
        op[1 * HWc] = acc[t].y + idv.y;
        op[2 * HWc] = acc[t].z + idv.z;
        op[3 * HWc] = acc[t].w + idv.w;
    }
}

// ---------------------------------------------------------------------------
// Fallback (Round-1 kernel): used only if ws_size is too small.
// ---------------------------------------------------------------------------
__global__ __launch_bounds__(256) void gridsample_warp_acc(
    const float* __restrict__ img, const float* __restrict__ cum_flow,
    const float* __restrict__ mask, const float* __restrict__ decay,
    float* __restrict__ out)
{
    const int w = threadIdx.x, h = blockIdx.x, t = blockIdx.y;
    const int pix = h * Wc + w;
    const float base_x = w * (2.0f / Wc) - 1.0f + 1.0f / Wc;
    const float base_y = h * (2.0f / Hc) - 1.0f + 1.0f / Hc;
    const float fxt = cum_flow[(t * 2 + 0) * HWc + pix];
    const float fyt = cum_flow[(t * 2 + 1) * HWc + pix];
    float acc[Cc];
#pragma unroll
    for (int c = 0; c < Cc; ++c) acc[c] = 0.0f;
    for (int k = 0; k <= t; ++k) {
        const float wkt = mask[t * Lc + k] * __expf(-DECAYc * decay[t * Lc + k]);
        const float fxk = cum_flow[(k * 2 + 0) * HWc + pix];
        const float fyk = cum_flow[(k * 2 + 1) * HWc + pix];
        float gx = base_x + (fxt - fxk);
        const float gy = base_y + (fyt - fyk);
        float m = gx + 1.0f;
        m -= 2.0f * floorf(m * 0.5f);
        gx = m - 1.0f;
        const float ix = (gx + 1.0f) * (Wc * 0.5f) - 0.5f;
        const float iy = (gy + 1.0f) * (Hc * 0.5f) - 0.5f;
        const float x0f = floorf(ix), y0f = floorf(iy);
        const float wx = ix - x0f, wy = iy - y0f;
        const int x0 = (int)x0f, y0 = (int)y0f;
        const int x0r = x0 & (Wc - 1), x1r = (x0 + 1) & (Wc - 1);
        const int y0c = min(max(y0, 0), Hc - 1), y1c = min(max(y0 + 1, 0), Hc - 1);
        const float a00 = wkt * (1.0f - wx) * (1.0f - wy);
        const float a01 = wkt * (1.0f - wx) * wy;
        const float a10 = wkt * wx * (1.0f - wy);
        const float a11 = wkt * wx * wy;
        const int o00 = y0c * Wc + x0r, o01 = y1c * Wc + x0r;
        const int o10 = y0c * Wc + x1r, o11 = y1c * Wc + x1r;
        const float* __restrict__ ik = img + (size_t)k * Cc * HWc;
#pragma unroll
        for (int c = 0; c < Cc; ++c) {
            const float* __restrict__ p = ik + c * HWc;
            acc[c] += p[o00] * a00 + p[o01] * a01 + p[o10] * a10 + p[o11] * a11;
        }
    }
    float* __restrict__ op = out + (size_t)t * Cc * HWc + pix;
#pragma unroll
    for (int c = 0; c < Cc; ++c) op[c * HWc] = acc[c];
}

extern "C" void kernel_launch(void* const* d_in, const int* in_sizes, int n_in,
                              void* d_out, int out_size, void* d_ws, size_t ws_size,
                              hipStream_t stream) {
    const float* img      = (const float*)d_in[0];
    const float* cum_flow = (const float*)d_in[1];
    const float* mask     = (const float*)d_in[2];
    const float* decay    = (const float*)d_in[3];
    float* out = (float*)d_out;

    const size_t imgT_bytes = (size_t)Lc * HWc * Cc * sizeof(float);  // 32 MB
    const size_t needed = imgT_bytes + 256;
    if (ws_size >= needed) {
        float* imgT = (float*)d_ws;
        unsigned int* done = (unsigned int*)((char*)d_ws + imgT_bytes);
        hipMemsetAsync(done, 0, sizeof(unsigned int), stream);
        gridsample_fused_sw<<<dim3(NBLK), 256, 0, stream>>>(
            img, cum_flow, mask, decay, imgT, done, out);
    } else {
        dim3 grid(Hc, Lc, 1);
        gridsample_warp_acc<<<grid, Wc, 0, stream>>>(img, cum_flow, mask, decay, out);
    }
}

// Round 8
// 150.501 us; speedup vs baseline: 1.4563x; 1.4563x over previous
//
#include <hip/hip_runtime.h>

constexpr int Lc = 16;
constexpr int Cc = 16;
constexpr int Hc = 128;
constexpr int Wc = 256;
constexpr float DECAYc = 0.1f;
constexpr int HWc = Hc * Wc;

// float -> bf16 bits, round-to-nearest-even (inputs are finite normals).
__device__ inline unsigned short f2bf(float f) {
    unsigned int u = __float_as_uint(f);
    u += 0x7fffu + ((u >> 16) & 1u);
    return (unsigned short)(u >> 16);
}
// packed ushort2 (bf16 pair) -> 2 floats
__device__ inline float2 bf2f2(unsigned int u) {
    return make_float2(__uint_as_float(u << 16),
                       __uint_as_float(u & 0xffff0000u));
}

// ---------------------------------------------------------------------------
// Kernel 1: transpose+convert img (L,C,H,W) f32 -> imgTb (L,H,W,C) bf16.
// Lane map: h2 = tid&1 (channels 8*h2..8*h2+7), wq = tid>>1 (128 px/iter).
// Reads coalesced per plane; writes: 2 lanes x 16B = one 32B pixel line,
// fully contiguous across the wave.
// ---------------------------------------------------------------------------
__global__ __launch_bounds__(256) void transpose_cvt_bf16(
    const float* __restrict__ img, unsigned short* __restrict__ imgTb)
{
    const int tid = threadIdx.x;
    const int h2 = tid & 1;
    const int wq = tid >> 1;             // 0..127
    const int kf  = blockIdx.x >> 5;     // 0..15
    const int px0 = (blockIdx.x & 31) * 1024;
    const float* __restrict__ srcb = img + (size_t)kf * Cc * HWc + (size_t)(8 * h2) * HWc;
#pragma unroll
    for (int rr = 0; rr < 8; ++rr) {
        const int px = px0 + rr * 128 + wq;
        float v[8];
#pragma unroll
        for (int c = 0; c < 8; ++c) v[c] = srcb[c * HWc + px];
        uint4 o;
        o.x = (unsigned int)f2bf(v[0]) | ((unsigned int)f2bf(v[1]) << 16);
        o.y = (unsigned int)f2bf(v[2]) | ((unsigned int)f2bf(v[3]) << 16);
        o.z = (unsigned int)f2bf(v[4]) | ((unsigned int)f2bf(v[5]) << 16);
        o.w = (unsigned int)f2bf(v[6]) | ((unsigned int)f2bf(v[7]) << 16);
        *(uint4*)(imgTb + ((size_t)kf * HWc + px) * Cc + 8 * h2) = o;
    }
}

// ---------------------------------------------------------------------------
// Chunk helper: for t in [T0, T0+3] (static), t>k (uniform): compute coords,
// then issue ALL gathers back-to-back (memory ILP), then consume.
// ---------------------------------------------------------------------------
template <int T0>
__device__ inline void do_chunk(
    int k, const unsigned short* __restrict__ bk, int q, int pix,
    const float* sx1, const float* sy1, float fxk, float fyk,
    const float* __restrict__ wtab, float4* acc)
{
    int   offs[4][4];
    float wts [4][4];
    uint2 ld  [4][4];

    // 1) coordinates + folded weights
#pragma unroll
    for (int j = 0; j < 4; ++j) {
        const int t = T0 + j;
        if (t >= Lc) continue;
        if (t > k) {
            const float wkt = wtab[t * Lc + k];
            float m = sx1[t] - fxk;
            m -= 2.0f * floorf(m * 0.5f);
            const float ix = m * (Wc * 0.5f) - 0.5f;
            const float iy = (sy1[t] - fyk) * (Hc * 0.5f) - 0.5f;
            const float x0f = floorf(ix);
            const float y0f = floorf(iy);
            const float wx = ix - x0f;
            const float wy = iy - y0f;
            const int x0 = (int)x0f;
            const int y0 = (int)y0f;
            const int x0r = x0 & (Wc - 1);
            const int x1r = (x0 + 1) & (Wc - 1);
            const int y0c = min(max(y0, 0), Hc - 1);
            const int y1c = min(max(y0 + 1, 0), Hc - 1);
            const float wb = wkt * wy;
            const float wa = wkt - wb;
            const float omx = 1.0f - wx;
            wts[j][0] = wa * omx;   // a00
            wts[j][1] = wa * wx;    // a10
            wts[j][2] = wb * omx;   // a01
            wts[j][3] = wb * wx;    // a11
            offs[j][0] = y0c * Wc + x0r;
            offs[j][1] = y0c * Wc + x1r;
            offs[j][2] = y1c * Wc + x0r;
            offs[j][3] = y1c * Wc + x1r;
        }
    }
    // 2) issue all loads (up to 16 in flight)
#pragma unroll
    for (int j = 0; j < 4; ++j) {
        const int t = T0 + j;
        if (t >= Lc) continue;
        if (t > k) {
#pragma unroll
            for (int n = 0; n < 4; ++n)
                ld[j][n] = ((const uint2*)(bk + (size_t)offs[j][n] * Cc))[q];
        }
    }
    // 3) convert + accumulate
#pragma unroll
    for (int j = 0; j < 4; ++j) {
        const int t = T0 + j;
        if (t >= Lc) continue;
        if (t > k) {
#pragma unroll
            for (int n = 0; n < 4; ++n) {
                const float2 f01 = bf2f2(ld[j][n].x);
                const float2 f23 = bf2f2(ld[j][n].y);
                const float a = wts[j][n];
                acc[t].x += a * f01.x;
                acc[t].y += a * f01.y;
                acc[t].z += a * f23.x;
                acc[t].w += a * f23.y;
            }
        }
    }
}

// ---------------------------------------------------------------------------
// Kernel 2: t-merged warp-accumulate over bf16 channels-last frames.
// 512 blocks (2/CU), strict k-lockstep, band-swizzle (b&7) for XCD L2
// locality. Lane = 4*wq+q: 4 lanes x 8B cover one pixel's 32B bf16 line.
// k==t identity handled in epilogue from fp32 img (exact, weight 1).
// ---------------------------------------------------------------------------
__global__ __launch_bounds__(256) void gridsample_bf16(
    const unsigned short* __restrict__ imgTb,  // (L, H, W, C) bf16
    const float* __restrict__ cum_flow,        // (L, 2, H, W)
    const float* __restrict__ mask,            // (L, L)
    const float* __restrict__ decay,           // (L, L)
    const float* __restrict__ img,             // (L, C, H, W) f32, identity
    float* __restrict__ out)                   // (L, C, H, W)
{
    __shared__ float wtab[Lc * Lc];
    const int tid = threadIdx.x;
    if (tid < Lc * Lc)
        wtab[tid] = mask[tid] * __expf(-DECAYc * decay[tid]);
    __syncthreads();

    const int q  = tid & 3;
    const int wq = tid >> 2;
    const int b = blockIdx.x;            // 0..511
    const int band = b & 7;
    const int sub  = b >> 3;
    const int h = band * 16 + (sub >> 2);
    const int w = (sub & 3) * 64 + wq;
    const int pix = h * Wc + w;

    const float base_x = w * (2.0f / Wc) - 1.0f + 1.0f / Wc;
    const float base_y = h * (2.0f / Hc) - 1.0f + 1.0f / Hc;

    float sx1[Lc], sy1[Lc];
#pragma unroll
    for (int t = 0; t < Lc; ++t) {
        sx1[t] = base_x + cum_flow[(t * 2 + 0) * HWc + pix] + 1.0f;
        sy1[t] = base_y + cum_flow[(t * 2 + 1) * HWc + pix] + 1.0f;
    }

    float4 acc[Lc];
#pragma unroll
    for (int t = 0; t < Lc; ++t) acc[t] = make_float4(0.f, 0.f, 0.f, 0.f);

    for (int k = 0; k < Lc - 1; ++k) {   // k==15 contributes only identity
        const float fxk = cum_flow[(k * 2 + 0) * HWc + pix];
        const float fyk = cum_flow[(k * 2 + 1) * HWc + pix];
        const unsigned short* __restrict__ bk = imgTb + (size_t)k * HWc * Cc;

        do_chunk<1> (k, bk, q, pix, sx1, sy1, fxk, fyk, wtab, acc);
        do_chunk<5> (k, bk, q, pix, sx1, sy1, fxk, fyk, wtab, acc);
        do_chunk<9> (k, bk, q, pix, sx1, sy1, fxk, fyk, wtab, acc);
        do_chunk<13>(k, bk, q, pix, sx1, sy1, fxk, fyk, wtab, acc);
    }

    // Epilogue: add exact fp32 identity sample (t==k, weight 1) and store.
#pragma unroll
    for (int t = 0; t < Lc; ++t) {
        const float* __restrict__ ip = img + ((size_t)t * Cc + 4 * q) * HWc + pix;
        float* __restrict__ op = out + ((size_t)t * Cc + 4 * q) * HWc + pix;
        op[0 * HWc] = acc[t].x + ip[0 * HWc];
        op[1 * HWc] = acc[t].y + ip[1 * HWc];
        op[2 * HWc] = acc[t].z + ip[2 * HWc];
        op[3 * HWc] = acc[t].w + ip[3 * HWc];
    }
}

// ---------------------------------------------------------------------------
// Fallback (Round-1 kernel): used only if ws_size is too small.
// ---------------------------------------------------------------------------
__global__ __launch_bounds__(256) void gridsample_warp_acc(
    const float* __restrict__ img, const float* __restrict__ cum_flow,
    const float* __restrict__ mask, const float* __restrict__ decay,
    float* __restrict__ out)
{
    const int w = threadIdx.x, h = blockIdx.x, t = blockIdx.y;
    const int pix = h * Wc + w;
    const float base_x = w * (2.0f / Wc) - 1.0f + 1.0f / Wc;
    const float base_y = h * (2.0f / Hc) - 1.0f + 1.0f / Hc;
    const float fxt = cum_flow[(t * 2 + 0) * HWc + pix];
    const float fyt = cum_flow[(t * 2 + 1) * HWc + pix];
    float acc[Cc];
#pragma unroll
    for (int c = 0; c < Cc; ++c) acc[c] = 0.0f;
    for (int k = 0; k <= t; ++k) {
        const float wkt = mask[t * Lc + k] * __expf(-DECAYc * decay[t * Lc + k]);
        const float fxk = cum_flow[(k * 2 + 0) * HWc + pix];
        const float fyk = cum_flow[(k * 2 + 1) * HWc + pix];
        float gx = base_x + (fxt - fxk);
        const float gy = base_y + (fyt - fyk);
        float m = gx + 1.0f;
        m -= 2.0f * floorf(m * 0.5f);
        gx = m - 1.0f;
        const float ix = (gx + 1.0f) * (Wc * 0.5f) - 0.5f;
        const float iy = (gy + 1.0f) * (Hc * 0.5f) - 0.5f;
        const float x0f = floorf(ix), y0f = floorf(iy);
        const float wx = ix - x0f, wy = iy - y0f;
        const int x0 = (int)x0f, y0 = (int)y0f;
        const int x0r = x0 & (Wc - 1), x1r = (x0 + 1) & (Wc - 1);
        const int y0c = min(max(y0, 0), Hc - 1), y1c = min(max(y0 + 1, 0), Hc - 1);
        const float a00 = wkt * (1.0f - wx) * (1.0f - wy);
        const float a01 = wkt * (1.0f - wx) * wy;
        const float a10 = wkt * wx * (1.0f - wy);
        const float a11 = wkt * wx * wy;
        const int o00 = y0c * Wc + x0r, o01 = y1c * Wc + x0r;
        const int o10 = y0c * Wc + x1r, o11 = y1c * Wc + x1r;
        const float* __restrict__ ik = img + (size_t)k * Cc * HWc;
#pragma unroll
        for (int c = 0; c < Cc; ++c) {
            const float* __restrict__ p = ik + c * HWc;
            acc[c] += p[o00] * a00 + p[o01] * a01 + p[o10] * a10 + p[o11] * a11;
        }
    }
    float* __restrict__ op = out + (size_t)t * Cc * HWc + pix;
#pragma unroll
    for (int c = 0; c < Cc; ++c) op[c * HWc] = acc[c];
}

extern "C" void kernel_launch(void* const* d_in, const int* in_sizes, int n_in,
                              void* d_out, int out_size, void* d_ws, size_t ws_size,
                              hipStream_t stream) {
    const float* img      = (const float*)d_in[0];
    const float* cum_flow = (const float*)d_in[1];
    const float* mask     = (const float*)d_in[2];
    const float* decay    = (const float*)d_in[3];
    float* out = (float*)d_out;

    const size_t needed = (size_t)Lc * HWc * Cc * sizeof(unsigned short);  // 16 MB
    if (ws_size >= needed) {
        unsigned short* imgTb = (unsigned short*)d_ws;
        transpose_cvt_bf16<<<dim3(512), 256, 0, stream>>>(img, imgTb);
        gridsample_bf16<<<dim3(512), 256, 0, stream>>>(
            imgTb, cum_flow, mask, decay, img, out);
    } else {
        dim3 grid(Hc, Lc, 1);
        gridsample_warp_acc<<<grid, Wc, 0, stream>>>(img, cum_flow, mask, decay, out);
    }
}